// Round 1
// baseline (751.118 us; speedup 1.0000x reference)
//
#include <hip/hip_runtime.h>
#include <math.h>

#define NN 100000
#define NE 1200000
#define CC 64
#define GG 256
#define RR 8
#define EPSF 1e-5f

// K1: mean-aggregation scatter. One wave (64 lanes) per edge, lane = channel.
__global__ __launch_bounds__(256) void k_edge(
    const float* __restrict__ x, const int* __restrict__ ei,
    float* __restrict__ agg, float* __restrict__ deg) {
  int tid = blockIdx.x * 256 + threadIdx.x;
  int e = tid >> 6;
  if (e >= NE) return;
  int c = tid & 63;
  int src = ei[e];
  int dst = ei[NE + e];
  float v = x[src * CC + c];
  atomicAdd(&agg[dst * CC + c], v);
  if (c == 0) atomicAdd(&deg[dst], 1.0f);
}

// K2: per-node h = (agg/deg)@Wl^T + bl + x@Wr^T, in-place over agg.
// Also accumulates per-graph sum(h) and node counts.
__global__ __launch_bounds__(256) void k_passA(
    const float* __restrict__ x, float* __restrict__ aggh,
    const float* __restrict__ deg, const int* __restrict__ batch,
    const float* __restrict__ Wl, const float* __restrict__ bl,
    const float* __restrict__ Wr,
    float* __restrict__ sumH, float* __restrict__ cnt) {
  __shared__ float WlT[CC * CC];  // WlT[k*64+c] = Wl[c][k]
  __shared__ float WrT[CC * CC];
  for (int idx = threadIdx.x; idx < CC * CC; idx += 256) {
    int c = idx >> 6, k = idx & 63;
    WlT[k * CC + c] = Wl[idx];
    WrT[k * CC + c] = Wr[idx];
  }
  __syncthreads();
  int wave = threadIdx.x >> 6;
  int lane = threadIdx.x & 63;
  int gw = blockIdx.x * 4 + wave;
  int nw = gridDim.x * 4;
  for (int i = gw; i < NN; i += nw) {
    float d = fmaxf(deg[i], 1.0f);
    float a = aggh[i * CC + lane] / d;
    float xv = x[i * CC + lane];
    float acc = bl[lane];
#pragma unroll
    for (int k = 0; k < CC; ++k) {
      float ak = __shfl(a, k);
      float xk = __shfl(xv, k);
      acc += ak * WlT[k * CC + lane] + xk * WrT[k * CC + lane];
    }
    aggh[i * CC + lane] = acc;
    int g = batch[i];
    atomicAdd(&sumH[g * CC + lane], acc);
    if (lane == 0) atomicAdd(&cnt[g], 1.0f);
  }
}

// K3: out = h - mean[batch]*alpha (in-place), accumulate per-graph sum(out^2).
__global__ __launch_bounds__(256) void k_passB(
    float* __restrict__ h, const int* __restrict__ batch,
    const float* __restrict__ sumH, const float* __restrict__ cnt,
    const float* __restrict__ alpha, float* __restrict__ sumSq) {
  int tid = blockIdx.x * 256 + threadIdx.x;
  int i = tid >> 6;
  if (i >= NN) return;
  int c = tid & 63;
  int g = batch[i];
  float cg = fmaxf(cnt[g], 1.0f);
  float mean = sumH[g * CC + c] / cg;
  float o = h[i * CC + c] - mean * alpha[c];
  h[i * CC + c] = o;
  atomicAdd(&sumSq[g * CC + c], o * o);
}

// K4: normalize, channel-attention gate on x, residual, relu -> d_out.
__global__ __launch_bounds__(256) void k_passC(
    const float* __restrict__ o, const float* __restrict__ x,
    const int* __restrict__ batch,
    const float* __restrict__ sumSq, const float* __restrict__ cnt,
    const float* __restrict__ gw, const float* __restrict__ gb,
    const float* __restrict__ a1w, const float* __restrict__ a1b,
    const float* __restrict__ a2w, const float* __restrict__ a2b,
    float* __restrict__ out) {
  int tid = blockIdx.x * 256 + threadIdx.x;
  int i = tid >> 6;
  if (i >= NN) return;
  int c = tid & 63;
  int g = batch[i];
  float cg = fmaxf(cnt[g], 1.0f);
  float var = sumSq[g * CC + c] / cg;
  float y = gw[c] * o[i * CC + c] * rsqrtf(var + EPSF) + gb[c];
  float xv = x[i * CC + c];
  // gate = sigmoid(relu(x @ a1w^T + a1b) @ a2w^T + a2b)
  float gacc = a2b[c];
#pragma unroll
  for (int r = 0; r < RR; ++r) {
    float p = xv * a1w[r * CC + c];
#pragma unroll
    for (int off = 32; off > 0; off >>= 1) p += __shfl_xor(p, off);
    float t = fmaxf(p + a1b[r], 0.0f);
    gacc += t * a2w[c * RR + r];
  }
  float gate = 1.0f / (1.0f + __expf(-gacc));
  out[i * CC + c] = fmaxf(y + gate * xv, 0.0f);
}

extern "C" void kernel_launch(void* const* d_in, const int* in_sizes, int n_in,
                              void* d_out, int out_size, void* d_ws, size_t ws_size,
                              hipStream_t stream) {
  const float* x       = (const float*)d_in[0];
  const int*   ei      = (const int*)d_in[1];
  const int*   batch   = (const int*)d_in[2];
  const float* Wl      = (const float*)d_in[3];
  const float* bl      = (const float*)d_in[4];
  const float* Wr      = (const float*)d_in[5];
  const float* gn_w    = (const float*)d_in[6];
  const float* gn_b    = (const float*)d_in[7];
  const float* gn_alpha= (const float*)d_in[8];
  const float* a1w     = (const float*)d_in[9];
  const float* a1b     = (const float*)d_in[10];
  const float* a2w     = (const float*)d_in[11];
  const float* a2b     = (const float*)d_in[12];
  float* out = (float*)d_out;

  float* ws   = (float*)d_ws;
  float* agg  = ws;                       // NN*CC : agg -> h -> gn_out (in-place)
  float* deg  = agg + (size_t)NN * CC;    // NN
  float* sumH = deg + NN;                 // GG*CC
  float* sumSq= sumH + GG * CC;           // GG*CC
  float* cnt  = sumSq + GG * CC;          // GG
  size_t zbytes = ((size_t)NN * CC + NN + 2 * GG * CC + GG) * sizeof(float);
  hipMemsetAsync(d_ws, 0, zbytes, stream);

  k_edge<<<(NE * 64 + 255) / 256, 256, 0, stream>>>(x, ei, agg, deg);
  k_passA<<<1024, 256, 0, stream>>>(x, agg, deg, batch, Wl, bl, Wr, sumH, cnt);
  k_passB<<<(NN * 64 + 255) / 256, 256, 0, stream>>>(agg, batch, sumH, cnt, gn_alpha, sumSq);
  k_passC<<<(NN * 64 + 255) / 256, 256, 0, stream>>>(agg, x, batch, sumSq, cnt,
                                                     gn_w, gn_b, a1w, a1b, a2w, a2b, out);
}

// Round 4
// 689.196 us; speedup vs baseline: 1.0898x; 1.0898x over previous
//
#include <hip/hip_runtime.h>
#include <math.h>

#define NN 100000
#define NE 1200000
#define CC 64
#define GG 256
#define RR 8
#define EPSF 1e-5f
#define NBLK 98  // ceil(NN/1024)

// ---------- CSR build ----------
__global__ __launch_bounds__(256) void k_deg(const int* __restrict__ ei,
                                             int* __restrict__ degcnt) {
  int e = blockIdx.x * 256 + threadIdx.x;
  if (e < NE) atomicAdd(&degcnt[ei[NE + e]], 1);
}

__global__ __launch_bounds__(256) void k_scan1(const int* __restrict__ deg,
                                               int* __restrict__ rowptr,
                                               int* __restrict__ bsum) {
  __shared__ int sh[256];
  int t = threadIdx.x, blk = blockIdx.x;
  int base = blk * 1024 + t * 4;
  int v0 = base + 0 < NN ? deg[base + 0] : 0;
  int v1 = base + 1 < NN ? deg[base + 1] : 0;
  int v2 = base + 2 < NN ? deg[base + 2] : 0;
  int v3 = base + 3 < NN ? deg[base + 3] : 0;
  int s = v0 + v1 + v2 + v3;
  sh[t] = s;
  __syncthreads();
  for (int d = 1; d < 256; d <<= 1) {
    int val = sh[t];
    int add = (t >= d) ? sh[t - d] : 0;
    __syncthreads();
    sh[t] = val + add;
    __syncthreads();
  }
  int excl = sh[t] - s;
  if (base + 0 < NN) rowptr[base + 0] = excl;
  if (base + 1 < NN) rowptr[base + 1] = excl + v0;
  if (base + 2 < NN) rowptr[base + 2] = excl + v0 + v1;
  if (base + 3 < NN) rowptr[base + 3] = excl + v0 + v1 + v2;
  if (t == 255) bsum[blk] = sh[255];
}

__global__ __launch_bounds__(128) void k_scan2(int* __restrict__ bsum) {
  __shared__ int sh[128];
  int t = threadIdx.x;
  int v = t < NBLK ? bsum[t] : 0;
  sh[t] = v;
  __syncthreads();
  for (int d = 1; d < 128; d <<= 1) {
    int val = sh[t];
    int add = (t >= d) ? sh[t - d] : 0;
    __syncthreads();
    sh[t] = val + add;
    __syncthreads();
  }
  if (t < NBLK) bsum[t] = sh[t] - v;  // exclusive, in place
}

__global__ __launch_bounds__(256) void k_scan3(int* __restrict__ rowptr,
                                               const int* __restrict__ bsum,
                                               int* __restrict__ cursor) {
  int t = threadIdx.x, blk = blockIdx.x;
  int base = blk * 1024 + t * 4;
  int off = bsum[blk];
#pragma unroll
  for (int q = 0; q < 4; ++q) {
    int i = base + q;
    if (i < NN) {
      int r = rowptr[i] + off;
      rowptr[i] = r;
      cursor[i] = r;
    }
  }
  if (blk == 0 && t == 0) rowptr[NN] = NE;
}

__global__ __launch_bounds__(256) void k_fill(const int* __restrict__ ei,
                                              int* __restrict__ cursor,
                                              int* __restrict__ csr) {
  int e = blockIdx.x * 256 + threadIdx.x;
  if (e < NE) {
    int src = ei[e], dst = ei[NE + e];
    int pos = atomicAdd(&cursor[dst], 1);
    csr[pos] = src;
  }
}

// ---------- gather: agg[i] = sum of x[src] over in-edges ----------
__global__ __launch_bounds__(256) void k_gather(const float* __restrict__ x,
                                                const int* __restrict__ csr,
                                                const int* __restrict__ rowptr,
                                                float* __restrict__ h) {
  int w = blockIdx.x * 4 + (threadIdx.x >> 6);
  int lane = threadIdx.x & 63;
  if (w >= NN) return;
  int s = rowptr[w], e = rowptr[w + 1];
  float acc = 0.0f;
  int j = s;
  for (; j + 3 < e; j += 4) {
    int s0 = csr[j], s1 = csr[j + 1], s2 = csr[j + 2], s3 = csr[j + 3];
    acc += x[(size_t)s0 * CC + lane];
    acc += x[(size_t)s1 * CC + lane];
    acc += x[(size_t)s2 * CC + lane];
    acc += x[(size_t)s3 * CC + lane];
  }
  for (; j < e; ++j) acc += x[(size_t)csr[j] * CC + lane];
  h[(size_t)w * CC + lane] = acc;
}

// ---------- passA: h = (agg/deg)@Wl^T + bl + x@Wr^T, in place over h ----------
__global__ __launch_bounds__(256) void k_passA(
    const float* __restrict__ x, float* h, const int* __restrict__ rowptr,
    const float* __restrict__ Wl, const float* __restrict__ bl,
    const float* __restrict__ Wr) {
  int i = blockIdx.x * 256 + threadIdx.x;
  if (i >= NN) return;
  float inv = 1.0f / fmaxf((float)(rowptr[i + 1] - rowptr[i]), 1.0f);
  float a[CC], xv[CC];
  const float4* ap = (const float4*)(h + (size_t)i * CC);
  const float4* xp = (const float4*)(x + (size_t)i * CC);
#pragma unroll
  for (int q = 0; q < 16; ++q) {
    float4 av = ap[q];
    float4 xq = xp[q];
    a[4 * q] = av.x * inv; a[4 * q + 1] = av.y * inv;
    a[4 * q + 2] = av.z * inv; a[4 * q + 3] = av.w * inv;
    xv[4 * q] = xq.x; xv[4 * q + 1] = xq.y;
    xv[4 * q + 2] = xq.z; xv[4 * q + 3] = xq.w;
  }
  float4* hp = (float4*)(h + (size_t)i * CC);
#pragma unroll 1
  for (int cg = 0; cg < 4; ++cg) {
    float acc[16];
#pragma unroll
    for (int j = 0; j < 16; ++j) acc[j] = bl[cg * 16 + j];
#pragma unroll
    for (int k = 0; k < CC; ++k) {
#pragma unroll
      for (int j = 0; j < 16; ++j) {
        int c = cg * 16 + j;
        acc[j] = fmaf(a[k], Wl[c * CC + k], acc[j]);
        acc[j] = fmaf(xv[k], Wr[c * CC + k], acc[j]);
      }
    }
#pragma unroll
    for (int q = 0; q < 4; ++q)
      hp[cg * 4 + q] = make_float4(acc[4 * q], acc[4 * q + 1],
                                   acc[4 * q + 2], acc[4 * q + 3]);
  }
}

// ---------- stats: segmented per-graph sum(h), sum(h^2), count (batch sorted) ----------
__global__ __launch_bounds__(256) void k_stats(const float* __restrict__ h,
                                               const int* __restrict__ batch,
                                               float* __restrict__ sumH,
                                               float* __restrict__ sumH2,
                                               float* __restrict__ cntg) {
  int w = blockIdx.x * 4 + (threadIdx.x >> 6);
  int lane = threadIdx.x & 63;
  int i0 = w * 64;
  if (i0 >= NN) return;
  int iend = i0 + 64 < NN ? i0 + 64 : NN;
  int gcur = batch[i0];
  float aH = 0.0f, aH2 = 0.0f;
  int run = 0;
  for (int i = i0; i < iend; ++i) {
    int g = batch[i];  // wave-uniform
    if (g != gcur) {
      atomicAdd(&sumH[(size_t)gcur * CC + lane], aH);
      atomicAdd(&sumH2[(size_t)gcur * CC + lane], aH2);
      if (lane == 0) atomicAdd(&cntg[gcur], (float)run);
      aH = 0.0f; aH2 = 0.0f; run = 0;
      gcur = g;
    }
    float v = h[(size_t)i * CC + lane];
    aH += v;
    aH2 += v * v;
    run++;
  }
  atomicAdd(&sumH[(size_t)gcur * CC + lane], aH);
  atomicAdd(&sumH2[(size_t)gcur * CC + lane], aH2);
  if (lane == 0) atomicAdd(&cntg[gcur], (float)run);
}

// ---------- passC: normalize (closed-form var) + gate + residual + relu ----------
__global__ __launch_bounds__(256) void k_passC(
    const float* __restrict__ h, const float* __restrict__ x,
    const int* __restrict__ batch, const float* __restrict__ sumH,
    const float* __restrict__ sumH2, const float* __restrict__ cntg,
    const float* __restrict__ gw, const float* __restrict__ gb,
    const float* __restrict__ alpha, const float* __restrict__ a1w,
    const float* __restrict__ a1b, const float* __restrict__ a2w,
    const float* __restrict__ a2b, float* __restrict__ out) {
  int i = blockIdx.x * 256 + threadIdx.x;
  if (i >= NN) return;
  int g = batch[i];
  float rn = 1.0f / fmaxf(cntg[g], 1.0f);
  float hv[CC], xv[CC];
  const float4* hp = (const float4*)(h + (size_t)i * CC);
  const float4* xp = (const float4*)(x + (size_t)i * CC);
#pragma unroll
  for (int q = 0; q < 16; ++q) {
    float4 a = hp[q];
    float4 b = xp[q];
    hv[4 * q] = a.x; hv[4 * q + 1] = a.y; hv[4 * q + 2] = a.z; hv[4 * q + 3] = a.w;
    xv[4 * q] = b.x; xv[4 * q + 1] = b.y; xv[4 * q + 2] = b.z; xv[4 * q + 3] = b.w;
  }
  // channel-attention hidden layer (weights wave-uniform -> s_load)
  float p[RR];
#pragma unroll
  for (int r = 0; r < RR; ++r) {
    float acc = a1b[r];
#pragma unroll
    for (int k = 0; k < CC; ++k) acc = fmaf(xv[k], a1w[r * CC + k], acc);
    p[r] = fmaxf(acc, 0.0f);
  }
  const float4* sHp = (const float4*)(sumH + (size_t)g * CC);
  const float4* sH2p = (const float4*)(sumH2 + (size_t)g * CC);
#pragma unroll
  for (int q = 0; q < 16; ++q) {
    float4 sH = sHp[q];
    float4 sH2 = sH2p[q];
    float sh[4] = {sH.x, sH.y, sH.z, sH.w};
    float sh2[4] = {sH2.x, sH2.y, sH2.z, sH2.w};
#pragma unroll
    for (int u = 0; u < 4; ++u) {
      int c = q * 4 + u;
      float mu = sh[u] * rn;
      float t = alpha[c] * mu;
      float var = sh2[u] * rn - 2.0f * mu * t + t * t;
      float o = hv[c] - t;
      float y = fmaf(gw[c] * o, rsqrtf(var + EPSF), gb[c]);
      float gacc = a2b[c];
#pragma unroll
      for (int r = 0; r < RR; ++r) gacc = fmaf(p[r], a2w[c * RR + r], gacc);
      float gate = 1.0f / (1.0f + __expf(-gacc));
      hv[c] = fmaxf(y + gate * xv[c], 0.0f);  // reuse hv as result
    }
  }
  float4* op = (float4*)(out + (size_t)i * CC);
#pragma unroll
  for (int q = 0; q < 16; ++q)
    op[q] = make_float4(hv[4 * q], hv[4 * q + 1], hv[4 * q + 2], hv[4 * q + 3]);
}

extern "C" void kernel_launch(void* const* d_in, const int* in_sizes, int n_in,
                              void* d_out, int out_size, void* d_ws, size_t ws_size,
                              hipStream_t stream) {
  const float* x        = (const float*)d_in[0];
  const int*   ei       = (const int*)d_in[1];
  const int*   batch    = (const int*)d_in[2];
  const float* Wl       = (const float*)d_in[3];
  const float* bl       = (const float*)d_in[4];
  const float* Wr       = (const float*)d_in[5];
  const float* gn_w     = (const float*)d_in[6];
  const float* gn_b     = (const float*)d_in[7];
  const float* gn_alpha = (const float*)d_in[8];
  const float* a1w      = (const float*)d_in[9];
  const float* a1b      = (const float*)d_in[10];
  const float* a2w      = (const float*)d_in[11];
  const float* a2b      = (const float*)d_in[12];
  float* out = (float*)d_out;

  // workspace layout (floats/ints, 4B units)
  float* h      = (float*)d_ws;                    // NN*CC (agg -> h in place)
  int*   degcnt = (int*)(h + (size_t)NN * CC);     // NN (reused as cursor)
  float* sumH   = (float*)(degcnt + NN);           // GG*CC
  float* sumH2  = sumH + GG * CC;                  // GG*CC
  float* cntg   = sumH2 + GG * CC;                 // GG
  int*   bsum   = (int*)(cntg + GG);               // 128
  int*   rowptr = bsum + 128;                      // NN+1
  int*   csr    = rowptr + NN + 1;                 // NE

  // zero: degcnt + sumH + sumH2 + cntg + bsum
  size_t zbytes = ((size_t)NN + 2 * GG * CC + GG + 128) * sizeof(int);
  hipMemsetAsync((void*)degcnt, 0, zbytes, stream);

  k_deg  <<<(NE + 255) / 256, 256, 0, stream>>>(ei, degcnt);
  k_scan1<<<NBLK, 256, 0, stream>>>(degcnt, rowptr, bsum);
  k_scan2<<<1, 128, 0, stream>>>(bsum);
  k_scan3<<<NBLK, 256, 0, stream>>>(rowptr, bsum, degcnt /*cursor*/);
  k_fill <<<(NE + 255) / 256, 256, 0, stream>>>(ei, degcnt /*cursor*/, csr);
  k_gather<<<(NN + 3) / 4, 256, 0, stream>>>(x, csr, rowptr, h);
  k_passA<<<(NN + 255) / 256, 256, 0, stream>>>(x, h, rowptr, Wl, bl, Wr);
  k_stats<<<((NN + 63) / 64 + 3) / 4, 256, 0, stream>>>(h, batch, sumH, sumH2, cntg);
  k_passC<<<(NN + 255) / 256, 256, 0, stream>>>(h, x, batch, sumH, sumH2, cntg,
                                                gn_w, gn_b, gn_alpha,
                                                a1w, a1b, a2w, a2b, out);
}

// Round 5
// 430.131 us; speedup vs baseline: 1.7463x; 1.6023x over previous
//
#include <hip/hip_runtime.h>
#include <math.h>

#define NN 100000
#define NE 1200000
#define CC 64
#define GG 256
#define RR 8
#define EPSF 1e-5f
#define NBLK 98  // ceil(NN/1024)

// ---------- CSR build ----------
__global__ __launch_bounds__(256) void k_deg(const int* __restrict__ ei,
                                             int* __restrict__ degcnt) {
  int e = blockIdx.x * 256 + threadIdx.x;
  if (e < NE) atomicAdd(&degcnt[ei[NE + e]], 1);
}

__global__ __launch_bounds__(256) void k_scan1(const int* __restrict__ deg,
                                               int* __restrict__ rowptr,
                                               int* __restrict__ bsum) {
  __shared__ int sh[256];
  int t = threadIdx.x, blk = blockIdx.x;
  int base = blk * 1024 + t * 4;
  int v0 = base + 0 < NN ? deg[base + 0] : 0;
  int v1 = base + 1 < NN ? deg[base + 1] : 0;
  int v2 = base + 2 < NN ? deg[base + 2] : 0;
  int v3 = base + 3 < NN ? deg[base + 3] : 0;
  int s = v0 + v1 + v2 + v3;
  sh[t] = s;
  __syncthreads();
  for (int d = 1; d < 256; d <<= 1) {
    int val = sh[t];
    int add = (t >= d) ? sh[t - d] : 0;
    __syncthreads();
    sh[t] = val + add;
    __syncthreads();
  }
  int excl = sh[t] - s;
  if (base + 0 < NN) rowptr[base + 0] = excl;
  if (base + 1 < NN) rowptr[base + 1] = excl + v0;
  if (base + 2 < NN) rowptr[base + 2] = excl + v0 + v1;
  if (base + 3 < NN) rowptr[base + 3] = excl + v0 + v1 + v2;
  if (t == 255) bsum[blk] = sh[255];
}

__global__ __launch_bounds__(128) void k_scan2(int* __restrict__ bsum) {
  __shared__ int sh[128];
  int t = threadIdx.x;
  int v = t < NBLK ? bsum[t] : 0;
  sh[t] = v;
  __syncthreads();
  for (int d = 1; d < 128; d <<= 1) {
    int val = sh[t];
    int add = (t >= d) ? sh[t - d] : 0;
    __syncthreads();
    sh[t] = val + add;
    __syncthreads();
  }
  if (t < NBLK) bsum[t] = sh[t] - v;  // exclusive, in place
}

__global__ __launch_bounds__(256) void k_scan3(int* __restrict__ rowptr,
                                               const int* __restrict__ bsum,
                                               int* __restrict__ cursor) {
  int t = threadIdx.x, blk = blockIdx.x;
  int base = blk * 1024 + t * 4;
  int off = bsum[blk];
#pragma unroll
  for (int q = 0; q < 4; ++q) {
    int i = base + q;
    if (i < NN) {
      int r = rowptr[i] + off;
      rowptr[i] = r;
      cursor[i] = r;
    }
  }
  if (blk == 0 && t == 0) rowptr[NN] = NE;
}

__global__ __launch_bounds__(256) void k_fill(const int* __restrict__ ei,
                                              int* __restrict__ cursor,
                                              int* __restrict__ csr) {
  int e = blockIdx.x * 256 + threadIdx.x;
  if (e < NE) {
    int src = ei[e], dst = ei[NE + e];
    int pos = atomicAdd(&cursor[dst], 1);
    csr[pos] = src;
  }
}

// ---------- gather: agg[i] = sum of x[src] over in-edges ----------
__global__ __launch_bounds__(256) void k_gather(const float* __restrict__ x,
                                                const int* __restrict__ csr,
                                                const int* __restrict__ rowptr,
                                                float* __restrict__ h) {
  int w = blockIdx.x * 4 + (threadIdx.x >> 6);
  int lane = threadIdx.x & 63;
  if (w >= NN) return;
  int s = rowptr[w], e = rowptr[w + 1];
  float acc = 0.0f;
  int j = s;
  for (; j + 3 < e; j += 4) {
    int s0 = csr[j], s1 = csr[j + 1], s2 = csr[j + 2], s3 = csr[j + 3];
    acc += x[(size_t)s0 * CC + lane];
    acc += x[(size_t)s1 * CC + lane];
    acc += x[(size_t)s2 * CC + lane];
    acc += x[(size_t)s3 * CC + lane];
  }
  for (; j < e; ++j) acc += x[(size_t)csr[j] * CC + lane];
  h[(size_t)w * CC + lane] = acc;
}

// ---------- passA: h = (agg/deg)@Wl^T + bl + x@Wr^T, in place over h ----------
// acc[64] held in VGPRs; inputs streamed in float4 chunks (no full row live
// -> no scratch spill; VGPR ~90). Weights thread-uniform -> s_load broadcast.
__global__ __launch_bounds__(256) void k_passA(
    const float* __restrict__ x, float* h, const int* __restrict__ rowptr,
    const float* __restrict__ Wl, const float* __restrict__ bl,
    const float* __restrict__ Wr) {
  int i = blockIdx.x * 256 + threadIdx.x;
  if (i >= NN) return;
  float inv = 1.0f / fmaxf((float)(rowptr[i + 1] - rowptr[i]), 1.0f);
  const float4* ap = (const float4*)(h + (size_t)i * CC);
  const float4* xp = (const float4*)(x + (size_t)i * CC);
  float acc[CC];
#pragma unroll
  for (int c = 0; c < CC; ++c) acc[c] = bl[c];
#pragma unroll 2
  for (int kb = 0; kb < 16; ++kb) {
    float4 a4 = ap[kb];
    float4 x4 = xp[kb];
    float a0 = a4.x * inv, a1 = a4.y * inv, a2 = a4.z * inv, a3 = a4.w * inv;
    int k0 = kb * 4;
#pragma unroll
    for (int c = 0; c < CC; ++c) {
      const float* wl = Wl + c * CC + k0;
      const float* wr = Wr + c * CC + k0;
      float t = acc[c];
      t = fmaf(a0, wl[0], t);
      t = fmaf(a1, wl[1], t);
      t = fmaf(a2, wl[2], t);
      t = fmaf(a3, wl[3], t);
      t = fmaf(x4.x, wr[0], t);
      t = fmaf(x4.y, wr[1], t);
      t = fmaf(x4.z, wr[2], t);
      t = fmaf(x4.w, wr[3], t);
      acc[c] = t;
    }
  }
  float4* hp = (float4*)(h + (size_t)i * CC);
#pragma unroll
  for (int q = 0; q < 16; ++q)
    hp[q] = make_float4(acc[4 * q], acc[4 * q + 1], acc[4 * q + 2], acc[4 * q + 3]);
}

// ---------- stats: segmented per-graph sum(h), sum(h^2), count (batch sorted) ----------
__global__ __launch_bounds__(256) void k_stats(const float* __restrict__ h,
                                               const int* __restrict__ batch,
                                               float* __restrict__ sumH,
                                               float* __restrict__ sumH2,
                                               float* __restrict__ cntg) {
  int w = blockIdx.x * 4 + (threadIdx.x >> 6);
  int lane = threadIdx.x & 63;
  int i0 = w * 64;
  if (i0 >= NN) return;
  int iend = i0 + 64 < NN ? i0 + 64 : NN;
  int gcur = batch[i0];
  float aH = 0.0f, aH2 = 0.0f;
  int run = 0;
  for (int i = i0; i < iend; ++i) {
    int g = batch[i];  // wave-uniform
    if (g != gcur) {
      atomicAdd(&sumH[(size_t)gcur * CC + lane], aH);
      atomicAdd(&sumH2[(size_t)gcur * CC + lane], aH2);
      if (lane == 0) atomicAdd(&cntg[gcur], (float)run);
      aH = 0.0f; aH2 = 0.0f; run = 0;
      gcur = g;
    }
    float v = h[(size_t)i * CC + lane];
    aH += v;
    aH2 += v * v;
    run++;
  }
  atomicAdd(&sumH[(size_t)gcur * CC + lane], aH);
  atomicAdd(&sumH2[(size_t)gcur * CC + lane], aH2);
  if (lane == 0) atomicAdd(&cntg[gcur], (float)run);
}

// ---------- passC: normalize (closed-form var) + gate + residual + relu ----------
// Only xv[64] (needed whole by the gate) + p[8] live; h/sumH/sumH2 streamed
// per-chunk with immediate store to out. VGPR ~90, no spill.
__global__ __launch_bounds__(256) void k_passC(
    const float* __restrict__ h, const float* __restrict__ x,
    const int* __restrict__ batch, const float* __restrict__ sumH,
    const float* __restrict__ sumH2, const float* __restrict__ cntg,
    const float* __restrict__ gw, const float* __restrict__ gb,
    const float* __restrict__ alpha, const float* __restrict__ a1w,
    const float* __restrict__ a1b, const float* __restrict__ a2w,
    const float* __restrict__ a2b, float* __restrict__ out) {
  int i = blockIdx.x * 256 + threadIdx.x;
  if (i >= NN) return;
  int g = batch[i];
  float rn = 1.0f / fmaxf(cntg[g], 1.0f);
  float xv[CC];
  const float4* xp = (const float4*)(x + (size_t)i * CC);
#pragma unroll
  for (int q = 0; q < 16; ++q) {
    float4 b = xp[q];
    xv[4 * q] = b.x; xv[4 * q + 1] = b.y; xv[4 * q + 2] = b.z; xv[4 * q + 3] = b.w;
  }
  // channel-attention hidden layer (weights thread-uniform -> s_load)
  float p[RR];
#pragma unroll
  for (int r = 0; r < RR; ++r) {
    float acc = a1b[r];
#pragma unroll
    for (int k = 0; k < CC; ++k) acc = fmaf(xv[k], a1w[r * CC + k], acc);
    p[r] = fmaxf(acc, 0.0f);
  }
  const float4* hp = (const float4*)(h + (size_t)i * CC);
  const float4* sHp = (const float4*)(sumH + (size_t)g * CC);
  const float4* sH2p = (const float4*)(sumH2 + (size_t)g * CC);
  float4* op = (float4*)(out + (size_t)i * CC);
#pragma unroll 4
  for (int q = 0; q < 16; ++q) {
    float4 h4 = hp[q];
    float4 sH = sHp[q];
    float4 sH2 = sH2p[q];
    float hv[4] = {h4.x, h4.y, h4.z, h4.w};
    float sh[4] = {sH.x, sH.y, sH.z, sH.w};
    float sh2[4] = {sH2.x, sH2.y, sH2.z, sH2.w};
    float res[4];
#pragma unroll
    for (int u = 0; u < 4; ++u) {
      int c = q * 4 + u;
      float mu = sh[u] * rn;
      float t = alpha[c] * mu;
      float var = sh2[u] * rn - 2.0f * mu * t + t * t;
      float o = hv[u] - t;
      float y = fmaf(gw[c] * o, rsqrtf(var + EPSF), gb[c]);
      float gacc = a2b[c];
#pragma unroll
      for (int r = 0; r < RR; ++r) gacc = fmaf(p[r], a2w[c * RR + r], gacc);
      float gate = 1.0f / (1.0f + __expf(-gacc));
      res[u] = fmaxf(y + gate * xv[c], 0.0f);
    }
    op[q] = make_float4(res[0], res[1], res[2], res[3]);
  }
}

extern "C" void kernel_launch(void* const* d_in, const int* in_sizes, int n_in,
                              void* d_out, int out_size, void* d_ws, size_t ws_size,
                              hipStream_t stream) {
  const float* x        = (const float*)d_in[0];
  const int*   ei       = (const int*)d_in[1];
  const int*   batch    = (const int*)d_in[2];
  const float* Wl       = (const float*)d_in[3];
  const float* bl       = (const float*)d_in[4];
  const float* Wr       = (const float*)d_in[5];
  const float* gn_w     = (const float*)d_in[6];
  const float* gn_b     = (const float*)d_in[7];
  const float* gn_alpha = (const float*)d_in[8];
  const float* a1w      = (const float*)d_in[9];
  const float* a1b      = (const float*)d_in[10];
  const float* a2w      = (const float*)d_in[11];
  const float* a2b      = (const float*)d_in[12];
  float* out = (float*)d_out;

  // workspace layout (floats/ints, 4B units)
  float* h      = (float*)d_ws;                    // NN*CC (agg -> h in place)
  int*   degcnt = (int*)(h + (size_t)NN * CC);     // NN (reused as cursor)
  float* sumH   = (float*)(degcnt + NN);           // GG*CC
  float* sumH2  = sumH + GG * CC;                  // GG*CC
  float* cntg   = sumH2 + GG * CC;                 // GG
  int*   bsum   = (int*)(cntg + GG);               // 128
  int*   rowptr = bsum + 128;                      // NN+1
  int*   csr    = rowptr + NN + 1;                 // NE

  // zero: degcnt + sumH + sumH2 + cntg + bsum
  size_t zbytes = ((size_t)NN + 2 * GG * CC + GG + 128) * sizeof(int);
  hipMemsetAsync((void*)degcnt, 0, zbytes, stream);

  k_deg  <<<(NE + 255) / 256, 256, 0, stream>>>(ei, degcnt);
  k_scan1<<<NBLK, 256, 0, stream>>>(degcnt, rowptr, bsum);
  k_scan2<<<1, 128, 0, stream>>>(bsum);
  k_scan3<<<NBLK, 256, 0, stream>>>(rowptr, bsum, degcnt /*cursor*/);
  k_fill <<<(NE + 255) / 256, 256, 0, stream>>>(ei, degcnt /*cursor*/, csr);
  k_gather<<<(NN + 3) / 4, 256, 0, stream>>>(x, csr, rowptr, h);
  k_passA<<<(NN + 255) / 256, 256, 0, stream>>>(x, h, rowptr, Wl, bl, Wr);
  k_stats<<<((NN + 63) / 64 + 3) / 4, 256, 0, stream>>>(h, batch, sumH, sumH2, cntg);
  k_passC<<<(NN + 255) / 256, 256, 0, stream>>>(h, x, batch, sumH, sumH2, cntg,
                                                gn_w, gn_b, gn_alpha,
                                                a1w, a1b, a2w, a2b, out);
}